// Round 19
// baseline (194.434 us; speedup 1.0000x reference)
//
#include <hip/hip_runtime.h>
#include <math.h>

constexpr int LSEQ = 2048;
constexpr int FEAT = 512;
constexpr int NH = 8;
constexpr int DM = 512;   // NH * HEAD_DIM
constexpr int NB = 2;

typedef __bf16 bf16x8 __attribute__((ext_vector_type(8)));
typedef unsigned short u16x8 __attribute__((ext_vector_type(8)));
typedef unsigned int u32x4 __attribute__((ext_vector_type(4)));
typedef float f32x4 __attribute__((ext_vector_type(4)));

#define EXPC 0.18033688011112042f    // log2(e)/8, folded into q at proj
#define L2TEN4 13.287712379549449f   // log2(10000)

// Raw v_exp_f32 (1 ulp; args bounded |s|<~22). Identical in pass1/pass2.
__device__ inline float ex2(float x) { return __builtin_amdgcn_exp2f(x); }

__device__ inline f32x4 mfma16(u16x8 a, u16x8 b, f32x4 c) {
  return __builtin_amdgcn_mfma_f32_16x16x32_bf16(
      __builtin_bit_cast(bf16x8, a), __builtin_bit_cast(bf16x8, b), c, 0, 0, 0);
}
__device__ inline unsigned cvtpk(float lo, float hi) {  // [bf16(lo) | bf16(hi)<<16], RNE
  unsigned r;
  asm("v_cvt_pk_bf16_f32 %0, %1, %2" : "=v"(r) : "v"(lo), "v"(hi));
  return r;
}
__device__ inline u16x8 ldbf8(const unsigned short* p) {
  return *reinterpret_cast<const u16x8*>(p);
}
// QK^T fragment chain — identical in pass1 and pass2 so scores are bit-identical.
__device__ inline f32x4 qk_chain(u16x8 a0, u16x8 a1, u16x8 q0, u16x8 q1) {
  f32x4 s = (f32x4){0.f, 0.f, 0.f, 0.f};
  s = mfma16(a0, q0, s);
  s = mfma16(a1, q1, s);
  return s;
}

// ---------------------------------------------------------------- prep_all
__global__ __launch_bounds__(256) void prep_all_kernel(
    const float* __restrict__ x, const float* __restrict__ Wq,
    const float* __restrict__ Wk, unsigned short* __restrict__ abuf,
    unsigned short* __restrict__ wbuf) {
  const int t = threadIdx.x;
  const int bid0 = blockIdx.x;
  if (bid0 >= 512) {   // W conversion: 256 blocks x 256 thr x 8 elems
    int i8 = (bid0 - 512) * 256 + t;
    size_t base = (size_t)i8 * 8;
    const float* src = (base < (size_t)512 * 512) ? Wq + base : Wk + (base - (size_t)512 * 512);
    float4 a = *(const float4*)src;
    float4 b4 = *(const float4*)(src + 4);
    *(uint2*)(wbuf + base) = make_uint2(cvtpk(a.x, a.y), cvtpk(a.z, a.w));
    *(uint2*)(wbuf + base + 4) = make_uint2(cvtpk(b4.x, b4.y), cvtpk(b4.z, b4.w));
    return;
  }
  __shared__ float As[64 * 68];
  const int ft = bid0 & 7, lt = (bid0 >> 3) & 31, b = bid0 >> 8;
  const int f0 = ft * 64, l0 = lt * 64;
#pragma unroll
  for (int rep = 0; rep < 4; ++rep) {
    int fl = rep * 16 + (t >> 4), l4 = (t & 15) * 4;
    int f = f0 + fl;
    float invt = ex2((float)(f >> 1) * (-L2TEN4 / 256.0f));  // 10000^(-i/256)
    float4 xv = *(const float4*)(x + ((size_t)b * FEAT + f) * LSEQ + l0 + l4);
    float a0 = (float)(l0 + l4 + 0) * invt;
    float a1 = (float)(l0 + l4 + 1) * invt;
    float a2 = (float)(l0 + l4 + 2) * invt;
    float a3 = (float)(l0 + l4 + 3) * invt;
    float4 pv;
    if (f & 1) { pv.x = __cosf(a0); pv.y = __cosf(a1); pv.z = __cosf(a2); pv.w = __cosf(a3); }
    else       { pv.x = __sinf(a0); pv.y = __sinf(a1); pv.z = __sinf(a2); pv.w = __sinf(a3); }
    *(float4*)&As[fl * 68 + l4] =
        make_float4(xv.x + pv.x, xv.y + pv.y, xv.z + pv.z, xv.w + pv.w);
  }
  __syncthreads();
  const int ll = t >> 2, fc = t & 3;
#pragma unroll
  for (int rep = 0; rep < 4; ++rep) {
    int fb = (fc + rep * 4) * 4;
    float v0 = As[(fb + 0) * 68 + ll];
    float v1 = As[(fb + 1) * 68 + ll];
    float v2 = As[(fb + 2) * 68 + ll];
    float v3 = As[(fb + 3) * 68 + ll];
    *(uint2*)(abuf + ((size_t)(b * LSEQ + l0 + ll)) * 512 + f0 + fb) =
        make_uint2(cvtpk(v0, v1), cvtpk(v2, v3));
  }
}

// ---------------------------------------------------------------- proj: [q|k] = A @ W^T + b, bf16 MFMA
__global__ __launch_bounds__(256) void proj_kernel(
    const unsigned short* __restrict__ abuf, const unsigned short* __restrict__ wbuf,
    const float* __restrict__ bq, const float* __restrict__ bk,
    unsigned short* __restrict__ qb, unsigned short* __restrict__ kb,
    unsigned short* __restrict__ kT) {
  const int t = threadIdx.x;
  const int c0 = blockIdx.x * 64;           // 0..960
  const int r0 = blockIdx.y * 64;           // 0..4032
  const int w = t >> 6, l = t & 63;
  const int lr = l & 15, g = l >> 4;
  const int c0w = c0 + (w >> 1) * 32;
  const int r0w = r0 + (w & 1) * 32;
  f32x4 acc[2][2];
#pragma unroll
  for (int i = 0; i < 2; ++i)
#pragma unroll
    for (int j = 0; j < 2; ++j) acc[i][j] = (f32x4){0.f, 0.f, 0.f, 0.f};
  for (int f0 = 0; f0 < FEAT; f0 += 32) {
    u16x8 a0 = ldbf8(wbuf + (size_t)(c0w + lr) * 512 + f0 + g * 8);
    u16x8 a1 = ldbf8(wbuf + (size_t)(c0w + 16 + lr) * 512 + f0 + g * 8);
    u16x8 b0 = ldbf8(abuf + (size_t)(r0w + lr) * 512 + f0 + g * 8);
    u16x8 b1 = ldbf8(abuf + (size_t)(r0w + 16 + lr) * 512 + f0 + g * 8);
    acc[0][0] = mfma16(a0, b0, acc[0][0]);
    acc[0][1] = mfma16(a0, b1, acc[0][1]);
    acc[1][0] = mfma16(a1, b0, acc[1][0]);
    acc[1][1] = mfma16(a1, b1, acc[1][1]);
  }
  const int isK = (c0 >= DM);
  const float* bias = isK ? bk : bq;
  unsigned short* ob = isK ? kb : qb;
  const float scale = isK ? 1.0f : EXPC;
  const int cb = c0w & (DM - 1);
#pragma unroll
  for (int ch = 0; ch < 2; ++ch) {
    int c = cb + ch * 16 + g * 4;
    float b0v = bias[c], b1v = bias[c + 1], b2v = bias[c + 2], b3v = bias[c + 3];
#pragma unroll
    for (int rh = 0; rh < 2; ++rh) {
      int r = r0w + rh * 16 + lr;
      f32x4 v = acc[ch][rh];
      uint2 u = make_uint2(cvtpk((v[0] + b0v) * scale, (v[1] + b1v) * scale),
                           cvtpk((v[2] + b2v) * scale, (v[3] + b3v) * scale));
      *(uint2*)(ob + (size_t)r * 512 + c) = u;
      if (isK) {
        int bsel = r >> 11, lq = r & (LSEQ - 1);
        unsigned short* kp = kT + ((size_t)(bsel * 512 + c)) * 2048 + lq;
        kp[0] = (unsigned short)(u.x & 0xffff);
        kp[2048] = (unsigned short)(u.x >> 16);
        kp[2 * 2048] = (unsigned short)(u.y & 0xffff);
        kp[3 * 2048] = (unsigned short)(u.y >> 16);
      }
    }
  }
}

// ---------------------------------------------------------------- pass 1: softmax denominators
__global__ __launch_bounds__(512) void pass1_kernel(
    const unsigned short* __restrict__ qb, const unsigned short* __restrict__ kb,
    float* __restrict__ lpart) {
  const int t = threadIdx.x;
  const int bid = blockIdx.x;
  const int sp = bid & 7, qt = (bid >> 3) & 31, b = bid >> 8;
  const int q0 = qt * 64;
  const int h = t >> 6, l = t & 63;
  const int lr = l & 15, g = l >> 4;
  u16x8 qf[4][2];
#pragma unroll
  for (int Mt = 0; Mt < 4; ++Mt)
#pragma unroll
    for (int dh = 0; dh < 2; ++dh)
      qf[Mt][dh] = ldbf8(qb + (size_t)(b * LSEQ + q0 + Mt * 16 + lr) * 512 + h * 64 + dh * 32 + g * 8);
  float sum[4] = {0.f, 0.f, 0.f, 0.f};
  for (int slab = 0; slab < 8; ++slab) {
    const int kk0 = sp * 256 + slab * 32;
    u16x8 af[2][2];
#pragma unroll
    for (int kh = 0; kh < 2; ++kh)
#pragma unroll
      for (int dh = 0; dh < 2; ++dh)
        af[kh][dh] = ldbf8(kb + (size_t)(b * LSEQ + kk0 + kh * 16 + lr) * 512 + h * 64 + dh * 32 + g * 8);
#pragma unroll
    for (int Mt = 0; Mt < 4; ++Mt)
#pragma unroll
      for (int kh = 0; kh < 2; ++kh) {
        f32x4 s = qk_chain(af[kh][0], af[kh][1], qf[Mt][0], qf[Mt][1]);
        sum[Mt] += ex2(s[0]) + ex2(s[1]) + ex2(s[2]) + ex2(s[3]);
      }
  }
#pragma unroll
  for (int Mt = 0; Mt < 4; ++Mt) {
    float v = sum[Mt];
    v += __shfl_xor(v, 16);
    v += __shfl_xor(v, 32);
    if ((l & 48) == 0)
      lpart[((size_t)((b * 8 + sp) * LSEQ) + q0 + Mt * 16 + lr) * 8 + h] = v;
  }
}

// ---------------------------------------------------------------- pass 2: attn write + PV
// R19: QT=16, S=2 -> grid 512 = 2 blocks/CU, retesting co-residency under the
// NEW regime (lgkm-only barriers so block A's store burst overlaps block B's
// compute; R16's regression predates that fix). LDS 37.4 KB dbuf. XCD pinning
// bid = qt*4 + b*2 + sp (per-XCD kb/kT slice 2 MB, L2-resident).
__global__ __launch_bounds__(512) void pass2_kernel(
    const unsigned short* __restrict__ qb, const unsigned short* __restrict__ kb,
    const unsigned short* __restrict__ kT, const float* __restrict__ lpart,
    float* __restrict__ attn, float* __restrict__ dist, float* __restrict__ distp) {
  __shared__ float Ps[2 * 16 * 292];   // dbuf [q][h*36 + kk], 37.4 KB
  __shared__ float linv_s[128];
  const int t = threadIdx.x;
  const int bid = blockIdx.x;
  const int qt = bid >> 2;             // 0..127
  const int b = (bid >> 1) & 1;
  const int sp = bid & 1;
  const int q0 = qt * 16;
  if (t < 128) {   // 16 q x 8 h denominators from the 8 kk-split partials
    int q = t >> 3, hh = t & 7;
    float s = 0.f;
#pragma unroll
    for (int p = 0; p < 8; ++p)
      s += lpart[((size_t)((b * 8 + p) * LSEQ) + q0 + q) * 8 + hh];
    linv_s[t] = 1.0f / s;
  }
  __syncthreads();
  const int h = t >> 6, l = t & 63;
  const int lr = l & 15, g = l >> 4;
  u16x8 qf[2];
#pragma unroll
  for (int dh = 0; dh < 2; ++dh)
    qf[dh] = ldbf8(qb + (size_t)(b * LSEQ + q0 + lr) * 512 + h * 64 + dh * 32 + g * 8);
  const float linv = linv_s[lr * 8 + h];   // lane-local: this lane's q-row is q0+lr

  f32x4 dacc[4];
#pragma unroll
  for (int Nd = 0; Nd < 4; ++Nd) dacc[Nd] = (f32x4){0.f, 0.f, 0.f, 0.f};
  const int kkb = sp * 1024;
  for (int slab = 0; slab < 32; ++slab) {
    const int kk0 = kkb + slab * 32;
    float* Pc = &Ps[(slab & 1) * 4672];
    u16x8 bt[4];
#pragma unroll
    for (int Nd = 0; Nd < 4; ++Nd)
      bt[Nd] = ldbf8(kT + (size_t)(b * 512 + h * 64 + Nd * 16 + lr) * 2048 + kk0 + g * 8);
#pragma unroll
    for (int kh = 0; kh < 2; ++kh) {
      const unsigned short* kp = kb + (size_t)(b * LSEQ + kk0 + kh * 16 + lr) * 512 + h * 64 + g * 8;
      u16x8 a0 = ldbf8(kp);
      u16x8 a1 = ldbf8(kp + 32);
      f32x4 s = qk_chain(a0, a1, qf[0], qf[1]);   // bit-identical to pass1
      f32x4 e = {ex2(s[0]) * linv, ex2(s[1]) * linv,
                 ex2(s[2]) * linv, ex2(s[3]) * linv};
      *(f32x4*)&Pc[lr * 292 + h * 36 + kh * 16 + g * 4] = e;
    }
    // lgkm-only barrier: LDS visible, attn stores NOT drained (retire async).
    asm volatile("s_waitcnt lgkmcnt(0)" ::: "memory");
    __builtin_amdgcn_s_barrier();
#pragma unroll
    for (int rep = 0; rep < 2; ++rep) {   // coalesced attn write: 16q x 32kk x 8h
      int F = rep * 512 + t;
      int q = F >> 6, kk = (F >> 1) & 31, hh = (F & 1) * 4;
      int pb = q * 292 + hh * 36 + kk;
      f32x4 v = {Pc[pb], Pc[pb + 36], Pc[pb + 72], Pc[pb + 108]};
      __builtin_nontemporal_store(v,
          (f32x4*)(attn + ((size_t)(b * LSEQ + q0 + q)) * (LSEQ * NH) + (size_t)(kk0 + kk) * 8 + hh));
    }
    {   // PV from normalized Ps
      int pb = lr * 292 + h * 36 + g * 8;
      f32x4 plo = *(const f32x4*)&Pc[pb];
      f32x4 phi = *(const f32x4*)&Pc[pb + 4];
      u32x4 pu = {cvtpk(plo[0], plo[1]), cvtpk(plo[2], plo[3]),
                  cvtpk(phi[0], phi[1]), cvtpk(phi[2], phi[3])};
      u16x8 pa = __builtin_bit_cast(u16x8, pu);
#pragma unroll
      for (int Nd = 0; Nd < 4; ++Nd)
        dacc[Nd] = mfma16(pa, bt[Nd], dacc[Nd]);
    }
    // single barrier per slab: dbuf Ps (this buffer's reads drain at the NEXT
    // slab's lgkmcnt(0) before it is rewritten two slabs later)
  }
  float* dp = sp ? distp : dist;
#pragma unroll
  for (int Nd = 0; Nd < 4; ++Nd)
#pragma unroll
    for (int r = 0; r < 4; ++r)
      dp[((size_t)(b * LSEQ + q0 + g * 4 + r)) * 512 + h * 64 + Nd * 16 + lr] = dacc[Nd][r];
}

// ---------------------------------------------------------------- combine: dist += distp
__global__ __launch_bounds__(256) void combine_kernel(const float* __restrict__ p,
                                                      float* __restrict__ dist) {
  int i4 = blockIdx.x * 256 + threadIdx.x;   // 0..524287
  const float4* p4 = (const float4*)p;
  float4 a = ((float4*)dist)[i4], c = p4[i4];
  ((float4*)dist)[i4] = make_float4(a.x + c.x, a.y + c.y, a.z + c.z, a.w + c.w);
}

extern "C" void kernel_launch(void* const* d_in, const int* in_sizes, int n_in,
                              void* d_out, int out_size, void* d_ws, size_t ws_size,
                              hipStream_t stream) {
  const float* x  = (const float*)d_in[0];
  const float* Wq = (const float*)d_in[1];
  const float* bq = (const float*)d_in[2];
  const float* Wk = (const float*)d_in[3];
  const float* bk = (const float*)d_in[4];
  float* out  = (float*)d_out;
  float* dist = out;
  float* attn = out + (size_t)NB * LSEQ * DM;
  float* ws = (float*)d_ws;
  // Workspace (float offsets):
  //   [0,1048576)        abuf (bf16)      — dead after proj
  //   [1048576,1310720)  wbuf (bf16)      — dead after proj
  //   [1310720,2097152)  pad              — keeps [0,2M) free for distp
  //   [2097152,3145728)  qb (bf16)
  //   [3145728,4194304)  kb (bf16)
  //   [4194304,5242880)  kT (bf16)
  //   [5242880,5505024)  lpart (f32)
  // distp recycles [0,2097152) — rewritten by prep_all every call (deterministic).
  unsigned short* abuf = (unsigned short*)(ws);
  unsigned short* wbuf = (unsigned short*)(ws + 1048576);
  unsigned short* qb   = (unsigned short*)(ws + 2097152);
  unsigned short* kb   = (unsigned short*)(ws + 3145728);
  unsigned short* kT   = (unsigned short*)(ws + 4194304);
  float* lpart = ws + 5242880;
  float* distp = ws;

  prep_all_kernel<<<768, 256, 0, stream>>>(x, Wq, Wk, abuf, wbuf);
  proj_kernel<<<dim3(16, 64), 256, 0, stream>>>(abuf, wbuf, bq, bk, qb, kb, kT);
  pass1_kernel<<<512, 512, 0, stream>>>(qb, kb, lpart);
  pass2_kernel<<<512, 512, 0, stream>>>(qb, kb, kT, lpart, attn, dist, distp);
  combine_kernel<<<2048, 256, 0, stream>>>(distp, dist);
}

// Round 20
// 154.265 us; speedup vs baseline: 1.2604x; 1.2604x over previous
//
#include <hip/hip_runtime.h>
#include <math.h>

constexpr int LSEQ = 2048;
constexpr int FEAT = 512;
constexpr int NH = 8;
constexpr int DM = 512;   // NH * HEAD_DIM
constexpr int NB = 2;

typedef __bf16 bf16x8 __attribute__((ext_vector_type(8)));
typedef unsigned short u16x8 __attribute__((ext_vector_type(8)));
typedef unsigned int u32x4 __attribute__((ext_vector_type(4)));
typedef float f32x4 __attribute__((ext_vector_type(4)));

#define EXPC 0.18033688011112042f    // log2(e)/8, folded into q at proj
#define L2TEN4 13.287712379549449f   // log2(10000)

// Raw v_exp_f32 (1 ulp; args bounded |s|<~22). Identical in pass1/pass2.
__device__ inline float ex2(float x) { return __builtin_amdgcn_exp2f(x); }

__device__ inline f32x4 mfma16(u16x8 a, u16x8 b, f32x4 c) {
  return __builtin_amdgcn_mfma_f32_16x16x32_bf16(
      __builtin_bit_cast(bf16x8, a), __builtin_bit_cast(bf16x8, b), c, 0, 0, 0);
}
__device__ inline unsigned cvtpk(float lo, float hi) {  // [bf16(lo) | bf16(hi)<<16], RNE
  unsigned r;
  asm("v_cvt_pk_bf16_f32 %0, %1, %2" : "=v"(r) : "v"(lo), "v"(hi));
  return r;
}
__device__ inline u16x8 ldbf8(const unsigned short* p) {
  return *reinterpret_cast<const u16x8*>(p);
}
// QK^T fragment chain — identical in pass1 and pass2 so scores are bit-identical.
__device__ inline f32x4 qk_chain(u16x8 a0, u16x8 a1, u16x8 q0, u16x8 q1) {
  f32x4 s = (f32x4){0.f, 0.f, 0.f, 0.f};
  s = mfma16(a0, q0, s);
  s = mfma16(a1, q1, s);
  return s;
}

// ---------------------------------------------------------------- prep_all
// bid<512: abuf[r][f] = bf16(x^T + pos), pos via HW __sinf/__cosf (validated R15:
// absmax unchanged). bid>=512: W (Wq rows 0-511, Wk rows 512-1023) -> bf16 wbuf.
__global__ __launch_bounds__(256) void prep_all_kernel(
    const float* __restrict__ x, const float* __restrict__ Wq,
    const float* __restrict__ Wk, unsigned short* __restrict__ abuf,
    unsigned short* __restrict__ wbuf) {
  const int t = threadIdx.x;
  const int bid0 = blockIdx.x;
  if (bid0 >= 512) {   // W conversion: 256 blocks x 256 thr x 8 elems
    int i8 = (bid0 - 512) * 256 + t;
    size_t base = (size_t)i8 * 8;
    const float* src = (base < (size_t)512 * 512) ? Wq + base : Wk + (base - (size_t)512 * 512);
    float4 a = *(const float4*)src;
    float4 b4 = *(const float4*)(src + 4);
    *(uint2*)(wbuf + base) = make_uint2(cvtpk(a.x, a.y), cvtpk(a.z, a.w));
    *(uint2*)(wbuf + base + 4) = make_uint2(cvtpk(b4.x, b4.y), cvtpk(b4.z, b4.w));
    return;
  }
  __shared__ float As[64 * 68];
  const int ft = bid0 & 7, lt = (bid0 >> 3) & 31, b = bid0 >> 8;
  const int f0 = ft * 64, l0 = lt * 64;
#pragma unroll
  for (int rep = 0; rep < 4; ++rep) {
    int fl = rep * 16 + (t >> 4), l4 = (t & 15) * 4;
    int f = f0 + fl;
    float invt = ex2((float)(f >> 1) * (-L2TEN4 / 256.0f));  // 10000^(-i/256)
    float4 xv = *(const float4*)(x + ((size_t)b * FEAT + f) * LSEQ + l0 + l4);
    float a0 = (float)(l0 + l4 + 0) * invt;
    float a1 = (float)(l0 + l4 + 1) * invt;
    float a2 = (float)(l0 + l4 + 2) * invt;
    float a3 = (float)(l0 + l4 + 3) * invt;
    float4 pv;
    if (f & 1) { pv.x = __cosf(a0); pv.y = __cosf(a1); pv.z = __cosf(a2); pv.w = __cosf(a3); }
    else       { pv.x = __sinf(a0); pv.y = __sinf(a1); pv.z = __sinf(a2); pv.w = __sinf(a3); }
    *(float4*)&As[fl * 68 + l4] =
        make_float4(xv.x + pv.x, xv.y + pv.y, xv.z + pv.z, xv.w + pv.w);
  }
  __syncthreads();
  const int ll = t >> 2, fc = t & 3;
#pragma unroll
  for (int rep = 0; rep < 4; ++rep) {
    int fb = (fc + rep * 4) * 4;
    float v0 = As[(fb + 0) * 68 + ll];
    float v1 = As[(fb + 1) * 68 + ll];
    float v2 = As[(fb + 2) * 68 + ll];
    float v3 = As[(fb + 3) * 68 + ll];
    *(uint2*)(abuf + ((size_t)(b * LSEQ + l0 + ll)) * 512 + f0 + fb) =
        make_uint2(cvtpk(v0, v1), cvtpk(v2, v3));
  }
}

// ---------------------------------------------------------------- proj: [q|k] = A @ W^T + b, bf16 MFMA
// q additionally scaled by EXPC (folds softmax 1/8 + log2e into the logits).
__global__ __launch_bounds__(256) void proj_kernel(
    const unsigned short* __restrict__ abuf, const unsigned short* __restrict__ wbuf,
    const float* __restrict__ bq, const float* __restrict__ bk,
    unsigned short* __restrict__ qb, unsigned short* __restrict__ kb,
    unsigned short* __restrict__ kT) {
  const int t = threadIdx.x;
  const int c0 = blockIdx.x * 64;           // 0..960
  const int r0 = blockIdx.y * 64;           // 0..4032
  const int w = t >> 6, l = t & 63;
  const int lr = l & 15, g = l >> 4;
  const int c0w = c0 + (w >> 1) * 32;
  const int r0w = r0 + (w & 1) * 32;
  f32x4 acc[2][2];
#pragma unroll
  for (int i = 0; i < 2; ++i)
#pragma unroll
    for (int j = 0; j < 2; ++j) acc[i][j] = (f32x4){0.f, 0.f, 0.f, 0.f};
  for (int f0 = 0; f0 < FEAT; f0 += 32) {
    u16x8 a0 = ldbf8(wbuf + (size_t)(c0w + lr) * 512 + f0 + g * 8);
    u16x8 a1 = ldbf8(wbuf + (size_t)(c0w + 16 + lr) * 512 + f0 + g * 8);
    u16x8 b0 = ldbf8(abuf + (size_t)(r0w + lr) * 512 + f0 + g * 8);
    u16x8 b1 = ldbf8(abuf + (size_t)(r0w + 16 + lr) * 512 + f0 + g * 8);
    acc[0][0] = mfma16(a0, b0, acc[0][0]);
    acc[0][1] = mfma16(a0, b1, acc[0][1]);
    acc[1][0] = mfma16(a1, b0, acc[1][0]);
    acc[1][1] = mfma16(a1, b1, acc[1][1]);
  }
  const int isK = (c0 >= DM);
  const float* bias = isK ? bk : bq;
  unsigned short* ob = isK ? kb : qb;
  const float scale = isK ? 1.0f : EXPC;
  const int cb = c0w & (DM - 1);
#pragma unroll
  for (int ch = 0; ch < 2; ++ch) {
    int c = cb + ch * 16 + g * 4;
    float b0v = bias[c], b1v = bias[c + 1], b2v = bias[c + 2], b3v = bias[c + 3];
#pragma unroll
    for (int rh = 0; rh < 2; ++rh) {
      int r = r0w + rh * 16 + lr;
      f32x4 v = acc[ch][rh];
      uint2 u = make_uint2(cvtpk((v[0] + b0v) * scale, (v[1] + b1v) * scale),
                           cvtpk((v[2] + b2v) * scale, (v[3] + b3v) * scale));
      *(uint2*)(ob + (size_t)r * 512 + c) = u;
      if (isK) {
        int bsel = r >> 11, lq = r & (LSEQ - 1);
        unsigned short* kp = kT + ((size_t)(bsel * 512 + c)) * 2048 + lq;
        kp[0] = (unsigned short)(u.x & 0xffff);
        kp[2048] = (unsigned short)(u.x >> 16);
        kp[2 * 2048] = (unsigned short)(u.y & 0xffff);
        kp[3 * 2048] = (unsigned short)(u.y >> 16);
      }
    }
  }
}

// ---------------------------------------------------------------- pass 1: softmax denominators
// Measured structure (R10): grid 512, QT=64 (Mt=4 ILP), kk-split 8.
__global__ __launch_bounds__(512) void pass1_kernel(
    const unsigned short* __restrict__ qb, const unsigned short* __restrict__ kb,
    float* __restrict__ lpart) {
  const int t = threadIdx.x;
  const int bid = blockIdx.x;
  const int sp = bid & 7, qt = (bid >> 3) & 31, b = bid >> 8;
  const int q0 = qt * 64;
  const int h = t >> 6, l = t & 63;
  const int lr = l & 15, g = l >> 4;
  u16x8 qf[4][2];
#pragma unroll
  for (int Mt = 0; Mt < 4; ++Mt)
#pragma unroll
    for (int dh = 0; dh < 2; ++dh)
      qf[Mt][dh] = ldbf8(qb + (size_t)(b * LSEQ + q0 + Mt * 16 + lr) * 512 + h * 64 + dh * 32 + g * 8);
  float sum[4] = {0.f, 0.f, 0.f, 0.f};
  for (int slab = 0; slab < 8; ++slab) {
    const int kk0 = sp * 256 + slab * 32;
    u16x8 af[2][2];
#pragma unroll
    for (int kh = 0; kh < 2; ++kh)
#pragma unroll
      for (int dh = 0; dh < 2; ++dh)
        af[kh][dh] = ldbf8(kb + (size_t)(b * LSEQ + kk0 + kh * 16 + lr) * 512 + h * 64 + dh * 32 + g * 8);
#pragma unroll
    for (int Mt = 0; Mt < 4; ++Mt)
#pragma unroll
      for (int kh = 0; kh < 2; ++kh) {
        f32x4 s = qk_chain(af[kh][0], af[kh][1], qf[Mt][0], qf[Mt][1]);
        sum[Mt] += ex2(s[0]) + ex2(s[1]) + ex2(s[2]) + ex2(s[3]);
      }
  }
#pragma unroll
  for (int Mt = 0; Mt < 4; ++Mt) {
    float v = sum[Mt];
    v += __shfl_xor(v, 16);
    v += __shfl_xor(v, 32);
    if ((l & 48) == 0)
      lpart[((size_t)((b * 8 + sp) * LSEQ) + q0 + Mt * 16 + lr) * 8 + h] = v;
  }
}

// ---------------------------------------------------------------- pass 2: attn write + PV
// R14 structure (QT=32, S=2, grid 256, XCD-pinned) + R17 lgkm-only barrier +
// R18 raw v_exp. Best measured configuration (154.4 us total).
__global__ __launch_bounds__(512) void pass2_kernel(
    const unsigned short* __restrict__ qb, const unsigned short* __restrict__ kb,
    const unsigned short* __restrict__ kT, const float* __restrict__ lpart,
    float* __restrict__ attn, float* __restrict__ dist, float* __restrict__ distp) {
  __shared__ float Ps[2 * 32 * 292];   // dbuf [q][h*36 + kk], 74.75 KB
  __shared__ float linv[256];
  const int t = threadIdx.x;
  const int bid = blockIdx.x;
  const int qt = bid >> 2;             // 0..63
  const int b = (bid >> 1) & 1;
  const int sp = bid & 1;
  const int q0 = qt * 32;
  if (t < 256) {
    int q = t >> 3, hh = t & 7;
    float s = 0.f;
#pragma unroll
    for (int p = 0; p < 8; ++p)
      s += lpart[((size_t)((b * 8 + p) * LSEQ) + q0 + q) * 8 + hh];
    linv[t] = 1.0f / s;
  }
  __syncthreads();
  const int h = t >> 6, l = t & 63;
  const int lr = l & 15, g = l >> 4;
  u16x8 qf[2][2];
#pragma unroll
  for (int Mt = 0; Mt < 2; ++Mt)
#pragma unroll
    for (int dh = 0; dh < 2; ++dh)
      qf[Mt][dh] = ldbf8(qb + (size_t)(b * LSEQ + q0 + Mt * 16 + lr) * 512 + h * 64 + dh * 32 + g * 8);
  float lv[2] = {linv[lr * 8 + h], linv[(16 + lr) * 8 + h]};
  f32x4 dacc[2][4];
#pragma unroll
  for (int Mt = 0; Mt < 2; ++Mt)
#pragma unroll
    for (int Nd = 0; Nd < 4; ++Nd) dacc[Mt][Nd] = (f32x4){0.f, 0.f, 0.f, 0.f};

  const int kkb = sp * 1024;
  for (int slab = 0; slab < 32; ++slab) {
    const int kk0 = kkb + slab * 32;
    float* Pc = &Ps[(slab & 1) * 9344];
    u16x8 af[2][2];
#pragma unroll
    for (int kh = 0; kh < 2; ++kh)
#pragma unroll
      for (int dh = 0; dh < 2; ++dh)
        af[kh][dh] = ldbf8(kb + (size_t)(b * LSEQ + kk0 + kh * 16 + lr) * 512 + h * 64 + dh * 32 + g * 8);
    u16x8 bt[4];
#pragma unroll
    for (int Nd = 0; Nd < 4; ++Nd)
      bt[Nd] = ldbf8(kT + (size_t)(b * 512 + h * 64 + Nd * 16 + lr) * 2048 + kk0 + g * 8);
#pragma unroll
    for (int Mt = 0; Mt < 2; ++Mt)
#pragma unroll
      for (int kh = 0; kh < 2; ++kh) {
        f32x4 s = qk_chain(af[kh][0], af[kh][1], qf[Mt][0], qf[Mt][1]);  // bit-identical to pass1
        f32x4 e = {ex2(s[0]) * lv[Mt], ex2(s[1]) * lv[Mt],
                   ex2(s[2]) * lv[Mt], ex2(s[3]) * lv[Mt]};
        *(f32x4*)&Pc[(Mt * 16 + lr) * 292 + h * 36 + kh * 16 + g * 4] = e;
      }
    // lgkmcnt(0)-only barrier — LDS visible to all waves; attn stores not drained.
    asm volatile("s_waitcnt lgkmcnt(0)" ::: "memory");
    __builtin_amdgcn_s_barrier();
#pragma unroll
    for (int rep = 0; rep < 4; ++rep) {   // coalesced attn write: 32q x 32kk x 8h
      int F = rep * 512 + t;
      int q = F >> 6, kk = (F >> 1) & 31, hh = (F & 1) * 4;
      int pb = q * 292 + hh * 36 + kk;
      f32x4 v = {Pc[pb], Pc[pb + 36], Pc[pb + 72], Pc[pb + 108]};
      __builtin_nontemporal_store(v,
          (f32x4*)(attn + ((size_t)(b * LSEQ + q0 + q)) * (LSEQ * NH) + (size_t)(kk0 + kk) * 8 + hh));
    }
#pragma unroll
    for (int Mt = 0; Mt < 2; ++Mt) {   // PV from normalized Ps
      int pb = (Mt * 16 + lr) * 292 + h * 36 + g * 8;
      f32x4 plo = *(const f32x4*)&Pc[pb];
      f32x4 phi = *(const f32x4*)&Pc[pb + 4];
      u32x4 pu = {cvtpk(plo[0], plo[1]), cvtpk(plo[2], plo[3]),
                  cvtpk(phi[0], phi[1]), cvtpk(phi[2], phi[3])};
      u16x8 pa = __builtin_bit_cast(u16x8, pu);
#pragma unroll
      for (int Nd = 0; Nd < 4; ++Nd)
        dacc[Mt][Nd] = mfma16(pa, bt[Nd], dacc[Mt][Nd]);
    }
    // single barrier per slab: double-buffered Ps (writes to this buffer recur
    // only after the NEXT slab's barrier, whose lgkmcnt(0) drains all ds_reads)
  }
  float* dp = sp ? distp : dist;
#pragma unroll
  for (int Mt = 0; Mt < 2; ++Mt)
#pragma unroll
    for (int Nd = 0; Nd < 4; ++Nd)
#pragma unroll
      for (int r = 0; r < 4; ++r)
        dp[((size_t)(b * LSEQ + q0 + Mt * 16 + g * 4 + r)) * 512 + h * 64 + Nd * 16 + lr] =
            dacc[Mt][Nd][r];
}

// ---------------------------------------------------------------- combine: dist += distp
// dist = 2,097,152 floats = 524,288 float4 -> grid 2048 x 256 exactly.
__global__ __launch_bounds__(256) void combine_kernel(const float* __restrict__ p,
                                                      float* __restrict__ dist) {
  int i4 = blockIdx.x * 256 + threadIdx.x;   // 0..524287
  const float4* p4 = (const float4*)p;
  float4 a = ((float4*)dist)[i4], c = p4[i4];
  ((float4*)dist)[i4] = make_float4(a.x + c.x, a.y + c.y, a.z + c.z, a.w + c.w);
}

extern "C" void kernel_launch(void* const* d_in, const int* in_sizes, int n_in,
                              void* d_out, int out_size, void* d_ws, size_t ws_size,
                              hipStream_t stream) {
  const float* x  = (const float*)d_in[0];
  const float* Wq = (const float*)d_in[1];
  const float* bq = (const float*)d_in[2];
  const float* Wk = (const float*)d_in[3];
  const float* bk = (const float*)d_in[4];
  float* out  = (float*)d_out;
  float* dist = out;
  float* attn = out + (size_t)NB * LSEQ * DM;
  float* ws = (float*)d_ws;
  // Workspace (float offsets):
  //   [0,1048576)        abuf (bf16)      — dead after proj
  //   [1048576,1310720)  wbuf (bf16)      — dead after proj
  //   [1310720,2097152)  pad              — keeps [0,2M) free for distp
  //   [2097152,3145728)  qb (bf16)
  //   [3145728,4194304)  kb (bf16)
  //   [4194304,5242880)  kT (bf16)
  //   [5242880,5505024)  lpart (f32)
  // distp recycles [0,2097152) — rewritten by prep_all every call (deterministic).
  unsigned short* abuf = (unsigned short*)(ws);
  unsigned short* wbuf = (unsigned short*)(ws + 1048576);
  unsigned short* qb   = (unsigned short*)(ws + 2097152);
  unsigned short* kb   = (unsigned short*)(ws + 3145728);
  unsigned short* kT   = (unsigned short*)(ws + 4194304);
  float* lpart = ws + 5242880;
  float* distp = ws;

  prep_all_kernel<<<768, 256, 0, stream>>>(x, Wq, Wk, abuf, wbuf);
  proj_kernel<<<dim3(16, 64), 256, 0, stream>>>(abuf, wbuf, bq, bk, qb, kb, kT);
  pass1_kernel<<<512, 512, 0, stream>>>(qb, kb, lpart);
  pass2_kernel<<<256, 512, 0, stream>>>(qb, kb, kT, lpart, attn, dist, distp);
  combine_kernel<<<2048, 256, 0, stream>>>(distp, dist);
}